// Round 1
// baseline (445.113 us; speedup 1.0000x reference)
//
#include <hip/hip_runtime.h>
#include <math.h>

// Region-layer loss (YOLOv2 style).
// Shapes: output (32, 425, 76, 76) f32 ; target (32, 250) f32 ; out: scalar f32.
#define NBATCH 32
#define NANCH  5
#define NCLS   80
#define NHH    76
#define NWW    76
#define MAXOBJ 50
#define CSZ    (NHH*NWW)          // 5776 cells per (b, anchor) plane
#define CELLS_PER_B (NANCH*CSZ)   // 28880
#define NCH    (5+NCLS)           // 85 channels per anchor
#define SILT   0.6f
#define CPT    4                  // cells per thread in the per-cell kernel
#define BLK    256

// ANCHORS_PX / 32, (w,h) pairs
__constant__ float c_aw[NANCH] = {18.3274f/32.0f, 59.9827f/32.0f, 106.8298f/32.0f, 252.2502f/32.0f, 312.6566f/32.0f};
__constant__ float c_ah[NANCH] = {21.6763f/32.0f, 66.0010f/32.0f, 175.1789f/32.0f, 112.8890f/32.0f, 293.3850f/32.0f};

__device__ __forceinline__ float sigf(float x) { return 1.0f / (1.0f + __expf(-x)); }

// ---------------------------------------------------------------------------
// Kernel A: per-object losses at owner cells (coord + obj-conf + class NLL).
// WARM==0 so these terms are zero everywhere except owner cells.
// Ownership = LAST valid object (JAX scatter last-wins) with same (bn,gj,gi).
// ---------------------------------------------------------------------------
__global__ void obj_kernel(const float* __restrict__ out,
                           const float* __restrict__ tgt,
                           float* __restrict__ loss) {
    __shared__ float T[MAXOBJ*5];
    __shared__ int   key[MAXOBJ];
    const int b = blockIdx.x;
    const int t = threadIdx.x;
    for (int i = t; i < MAXOBJ*5; i += 64) T[i] = tgt[(size_t)b*MAXOBJ*5 + i];
    __syncthreads();

    float gx=0.f, gy=0.f, gw=0.f, gh=0.f;
    int gi=0, gj=0, bn=0, cls=0;
    bool valid = false;
    if (t < MAXOBJ) {
        valid = true;                      // prefix-product validity
        for (int j = 0; j <= t; ++j) valid = valid && (T[j*5+1] > 0.0f);
        cls = (int)T[t*5+0];
        gx = T[t*5+1]*NWW; gy = T[t*5+2]*NHH;
        gw = T[t*5+3]*NWW; gh = T[t*5+4]*NHH;
        gi = (int)gx; gj = (int)gy;
        float best = -1.0f;
        for (int a = 0; a < NANCH; ++a) {  // co-centered anchor IoU argmax (first max wins)
            float inter = fminf(gw, c_aw[a]) * fminf(gh, c_ah[a]);
            float uni   = gw*gh + c_aw[a]*c_ah[a] - inter;
            float iou   = inter / uni;
            if (iou > best) { best = iou; bn = a; }
        }
        key[t] = valid ? (bn*CSZ + gj*NWW + gi) : (-1 - t);  // unique negatives for invalid
    }
    __syncthreads();

    if (t < MAXOBJ && valid) {
        bool owner = true;
        for (int o2 = t+1; o2 < MAXOBJ; ++o2)
            if (key[o2] == key[t]) { owner = false; break; }
        if (owner) {
            const size_t base = ((size_t)(b*NANCH + bn))*NCH*CSZ + (size_t)(gj*NWW + gi);
            float xr = out[base];
            float yr = out[base + (size_t)CSZ];
            float wr = out[base + (size_t)2*CSZ];
            float hr = out[base + (size_t)3*CSZ];
            float cr = out[base + (size_t)4*CSZ];
            float sx = sigf(xr), sy = sigf(yr), sc = sigf(cr);
            float pw = __expf(wr)*c_aw[bn], ph = __expf(hr)*c_ah[bn];
            float px = sx + (float)gi, py = sy + (float)gj;
            // best_iou(gt, pred_at)
            float iw = fmaxf(fminf(px+pw*0.5f, gx+gw*0.5f) - fmaxf(px-pw*0.5f, gx-gw*0.5f), 0.0f);
            float ih = fmaxf(fminf(py+ph*0.5f, gy+gh*0.5f) - fmaxf(py-ph*0.5f, gy-gh*0.5f), 0.0f);
            float inter = iw*ih;
            float biou  = inter / (pw*ph + gw*gh - inter);
            float tx = gx - (float)gi, ty = gy - (float)gj;
            float tw = __logf(gw / c_aw[bn]), th = __logf(gh / c_ah[bn]);
            float l = 0.5f*((sx-tx)*(sx-tx) + (sy-ty)*(sy-ty)
                          + (wr-tw)*(wr-tw) + (hr-th)*(hr-th));   // COORD_SCALE=1
            l += 2.5f*(sc - biou)*(sc - biou);                    // OBJ_SCALE/2 * (.)^2
            // class NLL via online logsumexp over 80 strided logits
            const float* lg = out + base + (size_t)5*CSZ;
            float m = -1e30f, s = 0.0f, lc = 0.0f;
            for (int c = 0; c < NCLS; ++c) {
                float L = lg[(size_t)c*CSZ];
                if (c == cls) lc = L;
                if (L > m) { s = s*__expf(m - L) + 1.0f; m = L; }
                else       { s += __expf(L - m); }
            }
            l += m + __logf(s) - lc;                              // CLASS_SCALE=1
            atomicAdd(loss, l);
        }
    }
}

// ---------------------------------------------------------------------------
// Kernel B: no-object conf loss over all 924,160 cells.
// silent  = exists valid GT with IoU(pred,gt) > 0.6  -> conf_mask 0
// owned   = cell was scattered OBJ_SCALE             -> handled in kernel A
// else    -> += conf^2 / 2
// Division-free: iou > 0.6  <=>  inter > 0.6*union (union > 0 always).
// ---------------------------------------------------------------------------
__global__ __launch_bounds__(BLK)
void cell_kernel(const float* __restrict__ out,
                 const float* __restrict__ tgt,
                 float* __restrict__ loss) {
    __shared__ float  T[MAXOBJ*5];
    __shared__ float4 sbox[MAXOBJ];    // x1,y1,x2,y2
    __shared__ float2 sak[MAXOBJ];     // area, key-as-float-bits
    __shared__ float  wsum[BLK/64];
    const int b = blockIdx.y;
    const int t = threadIdx.x;
    for (int i = t; i < MAXOBJ*5; i += BLK) T[i] = tgt[(size_t)b*MAXOBJ*5 + i];
    __syncthreads();
    if (t < MAXOBJ) {
        bool valid = true;
        for (int j = 0; j <= t; ++j) valid = valid && (T[j*5+1] > 0.0f);
        float gx = T[t*5+1]*NWW, gy = T[t*5+2]*NHH;
        float gw = T[t*5+3]*NWW, gh = T[t*5+4]*NHH;
        int bn = 0; float best = -1.0f;
        for (int a = 0; a < NANCH; ++a) {
            float inter = fminf(gw, c_aw[a]) * fminf(gh, c_ah[a]);
            float uni   = gw*gh + c_aw[a]*c_ah[a] - inter;
            float iou   = inter / uni;
            if (iou > best) { best = iou; bn = a; }
        }
        int k = valid ? (bn*CSZ + ((int)gy)*NWW + (int)gx) : (-1 - t);
        if (valid) {
            sbox[t] = make_float4(gx - gw*0.5f, gy - gh*0.5f, gx + gw*0.5f, gy + gh*0.5f);
            sak[t]  = make_float2(gw*gh, __int_as_float(k));
        } else {  // degenerate far-away box: inter==0, never silent, never owned
            sbox[t] = make_float4(3e8f, 3e8f, 3e8f, 3e8f);
            sak[t]  = make_float2(1.0f, __int_as_float(k));
        }
    }
    __syncthreads();

    const int c0 = blockIdx.x*(BLK*CPT) + t;
    float px1[CPT], py1[CPT], px2[CPT], py2[CPT], pa[CPT], crs[CPT];
    int cc[CPT]; bool live[CPT];
    #pragma unroll
    for (int k = 0; k < CPT; ++k) {
        const int c = c0 + k*BLK;
        cc[k] = c;
        live[k] = (c < CELLS_PER_B);
        float xr=0.f, yr=0.f, wr=0.f, hr=0.f, cr=0.f;
        int a = 0;
        if (live[k]) {
            a = c / CSZ;
            const int rem = c - a*CSZ;
            const size_t base = ((size_t)(b*NANCH + a))*NCH*CSZ + (size_t)rem;
            xr = out[base];
            yr = out[base + (size_t)CSZ];
            wr = out[base + (size_t)2*CSZ];
            hr = out[base + (size_t)3*CSZ];
            cr = out[base + (size_t)4*CSZ];
        }
        const int rem = c - a*CSZ;          // garbage ok for dead lanes (masked below)
        const int i = rem % NWW;
        const int j = rem / NWW;
        float pw = __expf(wr)*c_aw[a], ph = __expf(hr)*c_ah[a];
        float px = sigf(xr) + (float)i, py = sigf(yr) + (float)j;
        px1[k] = px - pw*0.5f; px2[k] = px + pw*0.5f;
        py1[k] = py - ph*0.5f; py2[k] = py + ph*0.5f;
        pa[k]  = pw*ph; crs[k] = cr;
    }

    bool sil[CPT], own[CPT];
    #pragma unroll
    for (int k = 0; k < CPT; ++k) { sil[k] = false; own[k] = false; }

    for (int o = 0; o < MAXOBJ; ++o) {      // wave-uniform LDS broadcasts
        const float4 bb = sbox[o];
        const float2 ak = sak[o];
        const int bkey = __float_as_int(ak.y);
        #pragma unroll
        for (int k = 0; k < CPT; ++k) {
            float iw = fmaxf(fminf(px2[k], bb.z) - fmaxf(px1[k], bb.x), 0.0f);
            float ih = fmaxf(fminf(py2[k], bb.w) - fmaxf(py1[k], bb.y), 0.0f);
            float inter = iw*ih;
            sil[k] = sil[k] || (inter > SILT*(pa[k] + ak.x - inter));
            own[k] = own[k] || (bkey == cc[k]);
        }
    }

    float l = 0.0f;
    #pragma unroll
    for (int k = 0; k < CPT; ++k) {
        if (live[k] && !own[k] && !sil[k]) {
            float sc = sigf(crs[k]);
            l += 0.5f*sc*sc;
        }
    }
    // block reduction: wave shuffle -> LDS -> single atomic per block
    for (int off = 32; off > 0; off >>= 1) l += __shfl_down(l, off);
    if ((t & 63) == 0) wsum[t >> 6] = l;
    __syncthreads();
    if (t == 0) {
        float s = 0.0f;
        for (int w = 0; w < BLK/64; ++w) s += wsum[w];
        atomicAdd(loss, s);
    }
}

extern "C" void kernel_launch(void* const* d_in, const int* in_sizes, int n_in,
                              void* d_out, int out_size, void* d_ws, size_t ws_size,
                              hipStream_t stream) {
    const float* out = (const float*)d_in[0];   // (32, 425, 76, 76) f32
    const float* tgt = (const float*)d_in[1];   // (32, 250) f32
    float* loss = (float*)d_out;                // scalar f32 (poisoned -> zero it)
    hipMemsetAsync(loss, 0, (size_t)out_size*sizeof(float), stream);
    obj_kernel<<<NBATCH, 64, 0, stream>>>(out, tgt, loss);
    dim3 grid((CELLS_PER_B + BLK*CPT - 1)/(BLK*CPT), NBATCH);
    cell_kernel<<<grid, BLK, 0, stream>>>(out, tgt, loss);
}

// Round 2
// 376.858 us; speedup vs baseline: 1.1811x; 1.1811x over previous
//
#include <hip/hip_runtime.h>
#include <math.h>

// Region-layer loss (YOLOv2 style), MI355X.
// output (32, 425, 76, 76) f32 ; target (32, 250) f32 ; out: scalar f32.
#define NBATCH 32
#define NANCH  5
#define NCLS   80
#define NHH    76
#define NWW    76
#define MAXOBJ 50
#define CSZ    (NHH*NWW)            // 5776
#define CELLS_PER_B (NANCH*CSZ)     // 28880
#define NCH    (5+NCLS)             // 85
#define CPT    4                    // consecutive cells per thread
#define BLK    256
#define TCG    (CELLS_PER_B/CPT)    // 7220 thread-cell groups per batch
#define NCBLK  ((TCG + BLK - 1)/BLK)// 29 cell blocks per batch item
#define NSLOT  256                  // padded accumulator slots in d_ws
#define SLOTSTRIDE 16               // 64B apart -> different L2 sectors

// ANCHORS_PX / 32
__constant__ float c_aw[NANCH] = {18.3274f/32.0f, 59.9827f/32.0f, 106.8298f/32.0f, 252.2502f/32.0f, 312.6566f/32.0f};
__constant__ float c_ah[NANCH] = {21.6763f/32.0f, 66.0010f/32.0f, 175.1789f/32.0f, 112.8890f/32.0f, 293.3850f/32.0f};

__device__ __forceinline__ float sigf(float x) { return 1.0f / (1.0f + __expf(-x)); }

// ---------------------------------------------------------------------------
// Fused kernel. grid = (NCBLK + MAXOBJ, NBATCH), block = 256.
//   blockIdx.x <  NCBLK : cell path — no-object conf loss over 1024 cells
//   blockIdx.x >= NCBLK : obj path  — one block per (b, object): coord + conf
//                         + class NLL at owner cell, minus the conf^2/2 the
//                         cell path added there (if that cell is non-silent).
// Ownership = LAST valid object with the same (best_n, gj, gi) key (np
// fancy-index assignment last-wins). Silent predicate, division-free:
//   iou > 0.6  <=>  inter > 0.375*(pa + area)   [0.6/1.6 = 0.375 exact]
// computed as inter - (0.375*pa + 0.375*area) > 0 in BOTH paths (identical
// fp expression forms, so the compensation matches the cell path exactly).
// ---------------------------------------------------------------------------
__global__ __launch_bounds__(BLK)
void region_kernel(const float* __restrict__ out,
                   const float* __restrict__ tgt,
                   float* __restrict__ acc) {
    __shared__ float  T[MAXOBJ*5];
    __shared__ float4 sbox[MAXOBJ];   // x1,y1,x2,y2
    __shared__ float  sthr[MAXOBJ];   // 0.375*area (1.0 for invalid)
    __shared__ int    keyS[MAXOBJ];
    __shared__ int    valS[MAXOBJ];
    __shared__ float  wsum[BLK/64];
    const int b = blockIdx.y;
    const int t = threadIdx.x;
    for (int i = t; i < MAXOBJ*5; i += BLK) T[i] = tgt[(size_t)b*MAXOBJ*5 + i];
    __syncthreads();

    const int slot = ((blockIdx.y*gridDim.x + blockIdx.x) & (NSLOT-1)) * SLOTSTRIDE;

    if (blockIdx.x < NCBLK) {
        // ================= cell path =================
        if (t < MAXOBJ) {
            bool valid = true;                       // cumprod(cx>0) prefix
            for (int j2 = 0; j2 <= t; ++j2) valid = valid && (T[j2*5+1] > 0.0f);
            float gx = T[t*5+1]*NWW, gy = T[t*5+2]*NHH;
            float gw = T[t*5+3]*NWW, gh = T[t*5+4]*NHH;
            if (valid) {
                sbox[t] = make_float4(gx - gw*0.5f, gy - gh*0.5f, gx + gw*0.5f, gy + gh*0.5f);
                float area = gw*gh;
                sthr[t] = 0.375f*area;
            } else {                                 // degenerate: inter==0 always
                sbox[t] = make_float4(3e8f, 3e8f, 3e8f, 3e8f);
                sthr[t] = 1.0f;
            }
        }
        __syncthreads();

        const int  tc   = blockIdx.x*BLK + t;        // thread-cell group
        const bool live = tc < TCG;
        const int  c    = tc*CPT;                    // first of 4 consecutive cells
        const int  a    = c / CSZ;                   // CSZ%4==0 -> uniform over the 4
        const int  rem  = c - a*CSZ;
        const int  jj   = rem / NWW;                 // NWW%4==0 -> row uniform too
        const int  i0   = rem - jj*NWW;

        float xr[CPT], yr[CPT], wr[CPT], hr[CPT], cf[CPT];
        if (live) {
            const float* base = out + ((size_t)(b*NANCH + a)*NCH)*CSZ + rem;  // 16B aligned
            float4 v;
            v = *(const float4*)(base);        xr[0]=v.x; xr[1]=v.y; xr[2]=v.z; xr[3]=v.w;
            v = *(const float4*)(base+  CSZ);  yr[0]=v.x; yr[1]=v.y; yr[2]=v.z; yr[3]=v.w;
            v = *(const float4*)(base+2*CSZ);  wr[0]=v.x; wr[1]=v.y; wr[2]=v.z; wr[3]=v.w;
            v = *(const float4*)(base+3*CSZ);  hr[0]=v.x; hr[1]=v.y; hr[2]=v.z; hr[3]=v.w;
            v = *(const float4*)(base+4*CSZ);  cf[0]=v.x; cf[1]=v.y; cf[2]=v.z; cf[3]=v.w;
        } else {
            #pragma unroll
            for (int k = 0; k < CPT; ++k) { xr[k]=yr[k]=wr[k]=hr[k]=cf[k]=0.0f; }
        }

        float px1[CPT], px2[CPT], py1[CPT], py2[CPT], qa[CPT], silv[CPT];
        #pragma unroll
        for (int k = 0; k < CPT; ++k) {
            float pw = __expf(wr[k])*c_aw[a], ph = __expf(hr[k])*c_ah[a];
            float px = sigf(xr[k]) + (float)(i0 + k);
            float py = sigf(yr[k]) + (float)jj;
            px1[k] = px - pw*0.5f; px2[k] = px + pw*0.5f;
            py1[k] = py - ph*0.5f; py2[k] = py + ph*0.5f;
            float pa = pw*ph;
            qa[k]  = 0.375f*pa;
            silv[k] = -1e30f;
        }

        for (int o = 0; o < MAXOBJ; ++o) {           // wave-uniform LDS broadcasts
            const float4 bb  = sbox[o];
            const float  thr = sthr[o];
            #pragma unroll
            for (int k = 0; k < CPT; ++k) {
                float iw = fminf(px2[k], bb.z) - fmaxf(px1[k], bb.x);
                float ih = fminf(py2[k], bb.w) - fmaxf(py1[k], bb.y);
                iw = fmaxf(iw, 0.0f); ih = fmaxf(ih, 0.0f);
                float inter = iw*ih;
                silv[k] = fmaxf(silv[k], inter - (qa[k] + thr));
            }
        }

        float l = 0.0f;
        if (live) {
            #pragma unroll
            for (int k = 0; k < CPT; ++k) {
                if (silv[k] <= 0.0f) {               // not silent
                    float sc = sigf(cf[k]);
                    l += 0.5f*sc*sc;
                }
            }
        }
        for (int off = 32; off > 0; off >>= 1) l += __shfl_down(l, off);
        if ((t & 63) == 0) wsum[t >> 6] = l;
        __syncthreads();
        if (t == 0) atomicAdd(acc + slot, wsum[0]+wsum[1]+wsum[2]+wsum[3]);

    } else {
        // ================= obj path: one block per (b, o) =================
        const int o = blockIdx.x - NCBLK;            // 0..49
        if (t < MAXOBJ) {
            bool valid = true;
            for (int j2 = 0; j2 <= t; ++j2) valid = valid && (T[j2*5+1] > 0.0f);
            valS[t] = valid ? 1 : 0;
            if (valid) {
                float gw = T[t*5+3]*NWW, gh = T[t*5+4]*NHH;
                int bn = 0; float best = -1.0f;
                for (int a = 0; a < NANCH; ++a) {    // first-max wins (argmax)
                    float inter = fminf(gw, c_aw[a]) * fminf(gh, c_ah[a]);
                    float uni   = gw*gh + c_aw[a]*c_ah[a] - inter;
                    float iou   = inter / uni;
                    if (iou > best) { best = iou; bn = a; }
                }
                int gi = (int)(T[t*5+1]*NWW), gj = (int)(T[t*5+2]*NHH);
                keyS[t] = bn*CSZ + gj*NWW + gi;
            } else keyS[t] = -1 - t;                 // unique, never matches
        }
        __syncthreads();
        if (t >= 64) return;                         // wave 0 only from here on
        if (!valS[o]) return;                        // uniform
        const int mykey = keyS[o];
        bool owner = true;
        for (int l2 = o+1; l2 < MAXOBJ; ++l2) owner = owner && (keyS[l2] != mykey);
        if (!owner) return;                          // last-wins: a later dup owns

        // uniform per-lane recompute of object o params
        const float gx = T[o*5+1]*NWW, gy = T[o*5+2]*NHH;
        const float gw = T[o*5+3]*NWW, gh = T[o*5+4]*NHH;
        const int   cls = (int)T[o*5+0];
        const int   bn  = mykey / CSZ;
        const int   gi  = (int)gx, gj = (int)gy;
        const float* base = out + ((size_t)(b*NANCH + bn)*NCH)*CSZ + (size_t)(gj*NWW + gi);
        const float xr = base[0], yv = base[CSZ], wv = base[2*(size_t)CSZ];
        const float hv = base[3*(size_t)CSZ], cv = base[4*(size_t)CSZ];
        const float sx = sigf(xr), sy = sigf(yv), sc = sigf(cv);
        const float pw = __expf(wv)*c_aw[bn], ph = __expf(hv)*c_ah[bn];
        const float px = sx + (float)gi, py = sy + (float)gj;
        const float pa = pw*ph;
        const float qa = 0.375f*pa;                  // same fp form as cell path

        // silent predicate at the owner cell: lane l tests GT l
        bool pred = false;
        if (t < MAXOBJ && valS[t]) {
            float ox = T[t*5+1]*NWW, oy = T[t*5+2]*NHH;
            float ow = T[t*5+3]*NWW, oh = T[t*5+4]*NHH;
            float iw = fminf(px + pw*0.5f, ox + ow*0.5f) - fmaxf(px - pw*0.5f, ox - ow*0.5f);
            float ih = fminf(py + ph*0.5f, oy + oh*0.5f) - fmaxf(py - ph*0.5f, oy - oh*0.5f);
            iw = fmaxf(iw, 0.0f); ih = fmaxf(ih, 0.0f);
            float inter = iw*ih;
            float area = ow*oh;
            float thr  = 0.375f*area;
            pred = (inter - (qa + thr)) > 0.0f;      // bitwise same predicate form
        }
        const bool silent = (__ballot(pred) != 0ull);

        // class NLL: lanes parallelize the 80-logit logsumexp
        const float* lg = base + (size_t)5*CSZ;
        const float L1 = lg[(size_t)t*CSZ];
        const float L2 = (t < NCLS-64) ? lg[(size_t)(t+64)*CSZ] : -1e30f;
        float m = fmaxf(L1, L2);
        for (int off = 32; off > 0; off >>= 1) m = fmaxf(m, __shfl_xor(m, off));
        float s = __expf(L1 - m) + ((t < NCLS-64) ? __expf(L2 - m) : 0.0f);
        for (int off = 32; off > 0; off >>= 1) s += __shfl_xor(s, off);
        const float lc = (cls < 64) ? __shfl(L1, cls) : __shfl(L2, cls - 64);

        if (t == 0) {
            float iw = fminf(px + pw*0.5f, gx + gw*0.5f) - fmaxf(px - pw*0.5f, gx - gw*0.5f);
            float ih = fminf(py + ph*0.5f, gy + gh*0.5f) - fmaxf(py - ph*0.5f, gy - gh*0.5f);
            iw = fmaxf(iw, 0.0f); ih = fmaxf(ih, 0.0f);
            float inter = iw*ih;
            float biou  = inter / (pa + gw*gh - inter);
            float tx = gx - (float)gi, ty = gy - (float)gj;
            float tw = __logf(gw / c_aw[bn]), th = __logf(gh / c_ah[bn]);
            float l = 0.5f*((sx-tx)*(sx-tx) + (sy-ty)*(sy-ty)
                          + (wv-tw)*(wv-tw) + (hv-th)*(hv-th));     // coord
            l += 2.5f*(sc - biou)*(sc - biou);                      // obj conf
            l += m + __logf(s) - lc;                                // class NLL
            if (!silent) l -= 0.5f*sc*sc;          // undo cell path's noobj term
            atomicAdd(acc + slot, l);
        }
    }
}

// Sum the NSLOT padded accumulator slots into the scalar output.
__global__ void reduce_kernel(const float* __restrict__ acc, float* __restrict__ loss) {
    __shared__ float wsum[NSLOT/64];
    const int t = threadIdx.x;
    float l = acc[t*SLOTSTRIDE];
    for (int off = 32; off > 0; off >>= 1) l += __shfl_down(l, off);
    if ((t & 63) == 0) wsum[t >> 6] = l;
    __syncthreads();
    if (t == 0) {
        float s = 0.0f;
        for (int w = 0; w < NSLOT/64; ++w) s += wsum[w];
        loss[0] = s;
    }
}

extern "C" void kernel_launch(void* const* d_in, const int* in_sizes, int n_in,
                              void* d_out, int out_size, void* d_ws, size_t ws_size,
                              hipStream_t stream) {
    const float* out = (const float*)d_in[0];   // (32, 425, 76, 76) f32
    const float* tgt = (const float*)d_in[1];   // (32, 250) f32
    float* acc  = (float*)d_ws;                 // NSLOT*SLOTSTRIDE floats, poisoned -> zero
    float* loss = (float*)d_out;
    hipMemsetAsync(acc, 0, (size_t)NSLOT*SLOTSTRIDE*sizeof(float), stream);
    dim3 grid(NCBLK + MAXOBJ, NBATCH);
    region_kernel<<<grid, BLK, 0, stream>>>(out, tgt, acc);
    reduce_kernel<<<1, NSLOT, 0, stream>>>(acc, loss);
}

// Round 3
// 376.270 us; speedup vs baseline: 1.1830x; 1.0016x over previous
//
#include <hip/hip_runtime.h>
#include <math.h>

// Region-layer loss (YOLOv2 style), MI355X.
// output (32, 425, 76, 76) f32 ; target (32, 250) f32 ; out: scalar f32.
#define NBATCH 32
#define NANCH  5
#define NCLS   80
#define NHH    76
#define NWW    76
#define MAXOBJ 50
#define CSZ    (NHH*NWW)            // 5776
#define CELLS_PER_B (NANCH*CSZ)     // 28880
#define NCH    (5+NCLS)             // 85
#define CPT    4                    // consecutive cells per thread
#define BLK    256
#define TCG    (CELLS_PER_B/CPT)    // 7220 thread-cell groups per batch
#define NCBLK  ((TCG + BLK - 1)/BLK)// 29 cell blocks per batch item
#define GX     (NCBLK + MAXOBJ)     // 79 blocks in x
#define NTOT   (GX*NBATCH)          // 2528 partial-sum slots

// ANCHORS_PX / 32
__constant__ float c_aw[NANCH] = {18.3274f/32.0f, 59.9827f/32.0f, 106.8298f/32.0f, 252.2502f/32.0f, 312.6566f/32.0f};
__constant__ float c_ah[NANCH] = {21.6763f/32.0f, 66.0010f/32.0f, 175.1789f/32.0f, 112.8890f/32.0f, 293.3850f/32.0f};

__device__ __forceinline__ float sigf(float x) { return 1.0f / (1.0f + __expf(-x)); }

// ---------------------------------------------------------------------------
// Fused kernel. grid = (GX, NBATCH), block = 256. Every block writes its
// partial sum to acc[blockIdx.y*GX + blockIdx.x] (no atomics, no memset —
// poison is always overwritten).
//   blockIdx.x <  NCBLK : cell path — no-object conf loss over 1024 cells
//   blockIdx.x >= NCBLK : obj path  — one block per (b, object): coord + conf
//                         + class NLL at owner cell, minus the conf^2/2 the
//                         cell path added there (if that cell is non-silent).
// Ownership = LAST valid object with the same (best_n, gj, gi) key (np
// fancy-index assignment last-wins). Silent predicate, division-free:
//   iou > 0.6  <=>  inter > 0.375*(pa + area)   [0.6/1.6 = 0.375 exact]
// computed as fmaf(iw, ih, -(qa + thr)) > 0 in BOTH paths (identical fp
// expression form, so the owner-cell compensation matches the cell path).
// ---------------------------------------------------------------------------
__global__ __launch_bounds__(BLK)
void region_kernel(const float* __restrict__ out,
                   const float* __restrict__ tgt,
                   float* __restrict__ acc) {
    __shared__ float  T[MAXOBJ*5];
    __shared__ float4 sbox[MAXOBJ];   // x1,y1,x2,y2
    __shared__ float  sthr[MAXOBJ];   // 0.375*area (1.0 for invalid)
    __shared__ int    keyS[MAXOBJ];
    __shared__ int    valS[MAXOBJ];
    __shared__ float  wsum[BLK/64];
    const int b = blockIdx.y;
    const int t = threadIdx.x;
    const int bid = b*GX + blockIdx.x;
    for (int i = t; i < MAXOBJ*5; i += BLK) T[i] = tgt[(size_t)b*MAXOBJ*5 + i];
    __syncthreads();

    if (blockIdx.x < NCBLK) {
        // ================= cell path =================
        if (t < MAXOBJ) {
            bool valid = true;                       // cumprod(cx>0) prefix
            for (int j2 = 0; j2 <= t; ++j2) valid = valid && (T[j2*5+1] > 0.0f);
            float gx = T[t*5+1]*NWW, gy = T[t*5+2]*NHH;
            float gw = T[t*5+3]*NWW, gh = T[t*5+4]*NHH;
            if (valid) {
                sbox[t] = make_float4(gx - gw*0.5f, gy - gh*0.5f, gx + gw*0.5f, gy + gh*0.5f);
                sthr[t] = 0.375f*(gw*gh);
            } else {                                 // degenerate: inter==0 always
                sbox[t] = make_float4(3e8f, 3e8f, 3e8f, 3e8f);
                sthr[t] = 1.0f;
            }
        }
        __syncthreads();

        const int  tc   = blockIdx.x*BLK + t;        // thread-cell group
        const bool live = tc < TCG;
        const int  c    = tc*CPT;                    // first of 4 consecutive cells
        const int  a    = c / CSZ;                   // CSZ%4==0 -> uniform over the 4
        const int  rem  = c - a*CSZ;
        const int  jj   = rem / NWW;                 // NWW%4==0 -> row uniform too
        const int  i0   = rem - jj*NWW;

        float xr[CPT], yr[CPT], wr[CPT], hr[CPT], cf[CPT];
        if (live) {
            const float* base = out + ((size_t)(b*NANCH + a)*NCH)*CSZ + rem;  // 16B aligned
            float4 v;
            v = *(const float4*)(base);        xr[0]=v.x; xr[1]=v.y; xr[2]=v.z; xr[3]=v.w;
            v = *(const float4*)(base+  CSZ);  yr[0]=v.x; yr[1]=v.y; yr[2]=v.z; yr[3]=v.w;
            v = *(const float4*)(base+2*CSZ);  wr[0]=v.x; wr[1]=v.y; wr[2]=v.z; wr[3]=v.w;
            v = *(const float4*)(base+3*CSZ);  hr[0]=v.x; hr[1]=v.y; hr[2]=v.z; hr[3]=v.w;
            v = *(const float4*)(base+4*CSZ);  cf[0]=v.x; cf[1]=v.y; cf[2]=v.z; cf[3]=v.w;
        } else {
            #pragma unroll
            for (int k = 0; k < CPT; ++k) { xr[k]=yr[k]=wr[k]=hr[k]=cf[k]=0.0f; }
        }

        float px1[CPT], px2[CPT], py1[CPT], py2[CPT], qa[CPT], silv[CPT];
        #pragma unroll
        for (int k = 0; k < CPT; ++k) {
            float pw = __expf(wr[k])*c_aw[a], ph = __expf(hr[k])*c_ah[a];
            float px = sigf(xr[k]) + (float)(i0 + k);
            float py = sigf(yr[k]) + (float)jj;
            px1[k] = px - pw*0.5f; px2[k] = px + pw*0.5f;
            py1[k] = py - ph*0.5f; py2[k] = py + ph*0.5f;
            qa[k]  = 0.375f*(pw*ph);
            silv[k] = -1e30f;
        }

        for (int o = 0; o < MAXOBJ; ++o) {           // wave-uniform LDS broadcasts
            const float4 bb  = sbox[o];
            const float  thr = sthr[o];
            #pragma unroll
            for (int k = 0; k < CPT; ++k) {
                float iw = fminf(px2[k], bb.z) - fmaxf(px1[k], bb.x);
                float ih = fminf(py2[k], bb.w) - fmaxf(py1[k], bb.y);
                iw = fmaxf(iw, 0.0f); ih = fmaxf(ih, 0.0f);
                silv[k] = fmaxf(silv[k], fmaf(iw, ih, -(qa[k] + thr)));
            }
        }

        float l = 0.0f;
        if (live) {
            #pragma unroll
            for (int k = 0; k < CPT; ++k) {
                if (silv[k] <= 0.0f) {               // not silent
                    float sc = sigf(cf[k]);
                    l += 0.5f*sc*sc;
                }
            }
        }
        for (int off = 32; off > 0; off >>= 1) l += __shfl_down(l, off);
        if ((t & 63) == 0) wsum[t >> 6] = l;
        __syncthreads();
        if (t == 0) acc[bid] = wsum[0]+wsum[1]+wsum[2]+wsum[3];

    } else {
        // ================= obj path: one block per (b, o) =================
        const int o = blockIdx.x - NCBLK;            // 0..49
        if (t < MAXOBJ) {
            bool valid = true;
            for (int j2 = 0; j2 <= t; ++j2) valid = valid && (T[j2*5+1] > 0.0f);
            valS[t] = valid ? 1 : 0;
            if (valid) {
                float gw = T[t*5+3]*NWW, gh = T[t*5+4]*NHH;
                int bn = 0; float best = -1.0f;
                for (int a = 0; a < NANCH; ++a) {    // first-max wins (argmax)
                    float inter = fminf(gw, c_aw[a]) * fminf(gh, c_ah[a]);
                    float uni   = gw*gh + c_aw[a]*c_ah[a] - inter;
                    float iou   = inter / uni;
                    if (iou > best) { best = iou; bn = a; }
                }
                int gi = (int)(T[t*5+1]*NWW), gj = (int)(T[t*5+2]*NHH);
                keyS[t] = bn*CSZ + gj*NWW + gi;
            } else keyS[t] = -1 - t;                 // unique, never matches
        }
        __syncthreads();
        if (t >= 64) return;                         // wave 0 only from here on

        float partial = 0.0f;
        const int mykey = keyS[o];
        bool owner = valS[o] != 0;                   // wave-uniform
        for (int l2 = o+1; l2 < MAXOBJ; ++l2) owner = owner && (keyS[l2] != mykey);
        if (owner) {                                 // uniform branch
            // uniform per-lane recompute of object o params
            const float gx = T[o*5+1]*NWW, gy = T[o*5+2]*NHH;
            const float gw = T[o*5+3]*NWW, gh = T[o*5+4]*NHH;
            const int   cls = (int)T[o*5+0];
            const int   bn  = mykey / CSZ;
            const int   gi  = (int)gx, gj = (int)gy;
            const float* base = out + ((size_t)(b*NANCH + bn)*NCH)*CSZ + (size_t)(gj*NWW + gi);
            const float xr = base[0], yv = base[CSZ], wv = base[2*(size_t)CSZ];
            const float hv = base[3*(size_t)CSZ], cv = base[4*(size_t)CSZ];
            const float sx = sigf(xr), sy = sigf(yv), sc = sigf(cv);
            const float pw = __expf(wv)*c_aw[bn], ph = __expf(hv)*c_ah[bn];
            const float px = sx + (float)gi, py = sy + (float)gj;
            const float qa = 0.375f*(pw*ph);         // same fp form as cell path

            // silent predicate at the owner cell: lane l tests GT l
            bool pred = false;
            if (t < MAXOBJ && valS[t]) {
                float ox = T[t*5+1]*NWW, oy = T[t*5+2]*NHH;
                float ow = T[t*5+3]*NWW, oh = T[t*5+4]*NHH;
                float iw = fminf(px + pw*0.5f, ox + ow*0.5f) - fmaxf(px - pw*0.5f, ox - ow*0.5f);
                float ih = fminf(py + ph*0.5f, oy + oh*0.5f) - fmaxf(py - ph*0.5f, oy - oh*0.5f);
                iw = fmaxf(iw, 0.0f); ih = fmaxf(ih, 0.0f);
                float thr = 0.375f*(ow*oh);
                pred = fmaf(iw, ih, -(qa + thr)) > 0.0f;   // same predicate form
            }
            const bool silent = (__ballot(pred) != 0ull);

            // class NLL: lanes parallelize the 80-logit logsumexp
            const float* lg = base + (size_t)5*CSZ;
            const float L1 = lg[(size_t)t*CSZ];
            const float L2 = (t < NCLS-64) ? lg[(size_t)(t+64)*CSZ] : -1e30f;
            float m = fmaxf(L1, L2);
            for (int off = 32; off > 0; off >>= 1) m = fmaxf(m, __shfl_xor(m, off));
            float s = __expf(L1 - m) + ((t < NCLS-64) ? __expf(L2 - m) : 0.0f);
            for (int off = 32; off > 0; off >>= 1) s += __shfl_xor(s, off);
            const float lc = (cls < 64) ? __shfl(L1, cls) : __shfl(L2, cls - 64);

            if (t == 0) {
                float iw = fminf(px + pw*0.5f, gx + gw*0.5f) - fmaxf(px - pw*0.5f, gx - gw*0.5f);
                float ih = fminf(py + ph*0.5f, gy + gh*0.5f) - fmaxf(py - ph*0.5f, gy - gh*0.5f);
                iw = fmaxf(iw, 0.0f); ih = fmaxf(ih, 0.0f);
                float inter = iw*ih;
                float biou  = inter / (pw*ph + gw*gh - inter);
                float tx = gx - (float)gi, ty = gy - (float)gj;
                float tw = __logf(gw / c_aw[bn]), th = __logf(gh / c_ah[bn]);
                float l = 0.5f*((sx-tx)*(sx-tx) + (sy-ty)*(sy-ty)
                              + (wv-tw)*(wv-tw) + (hv-th)*(hv-th));     // coord
                l += 2.5f*(sc - biou)*(sc - biou);                      // obj conf
                l += m + __logf(s) - lc;                                // class NLL
                if (!silent) l -= 0.5f*sc*sc;        // undo cell path's noobj term
                partial = l;
            }
        }
        if (t == 0) acc[bid] = partial;
    }
}

// Sum the NTOT per-block partials into the scalar output.
__global__ __launch_bounds__(256)
void reduce_kernel(const float* __restrict__ acc, float* __restrict__ loss) {
    __shared__ float wsum[4];
    const int t = threadIdx.x;
    float l = 0.0f;
    for (int i = t; i < NTOT; i += 256) l += acc[i];
    for (int off = 32; off > 0; off >>= 1) l += __shfl_down(l, off);
    if ((t & 63) == 0) wsum[t >> 6] = l;
    __syncthreads();
    if (t == 0) loss[0] = wsum[0]+wsum[1]+wsum[2]+wsum[3];
}

extern "C" void kernel_launch(void* const* d_in, const int* in_sizes, int n_in,
                              void* d_out, int out_size, void* d_ws, size_t ws_size,
                              hipStream_t stream) {
    const float* out = (const float*)d_in[0];   // (32, 425, 76, 76) f32
    const float* tgt = (const float*)d_in[1];   // (32, 250) f32
    float* acc  = (float*)d_ws;                 // NTOT per-block partials (no memset needed)
    float* loss = (float*)d_out;
    dim3 grid(GX, NBATCH);
    region_kernel<<<grid, BLK, 0, stream>>>(out, tgt, acc);
    reduce_kernel<<<1, 256, 0, stream>>>(acc, loss);
}